// Round 22
// baseline (138.751 us; speedup 1.0000x reference)
//
#include <hip/hip_runtime.h>
#include <hip/hip_bf16.h>

typedef __attribute__((ext_vector_type(8))) short bf16x8;
typedef __attribute__((ext_vector_type(4))) float f32x4;

__device__ __forceinline__ float sigmoidf_(float x){ return 1.0f/(1.0f+__expf(-x)); }
__device__ __forceinline__ float tanhf_(float x){ return 1.0f - 2.0f/(1.0f+__expf(2.0f*x)); }
__device__ __forceinline__ unsigned short f2bf(float f){
    __hip_bfloat16 b = __float2bfloat16(f);
    return *reinterpret_cast<unsigned short*>(&b);
}
__device__ __forceinline__ float bf2f(unsigned short u){
    __hip_bfloat16 b = *reinterpret_cast<__hip_bfloat16*>(&u);
    return __bfloat162float(b);
}
// async global->LDS, 16B per lane; LDS dest = wave-uniform base (+lane*16 implicit)
__device__ __forceinline__ void gload_lds16(const void* gsrc, void* ldst){
    __builtin_amdgcn_global_load_lds(
        (const __attribute__((address_space(1))) unsigned int*)gsrc,
        (__attribute__((address_space(3))) unsigned int*)ldst,
        16, 0, 0);
}

// ---------------------------------------------------------------------------
// Layouts (identical to R21 — verified):
//  Bg (ushort):
//   X slabs 0..63 (per-o, SINGLE bf16 plane): 10752 ush = [21 slots][4 qr][16 j][8 e].
//     kk<18 -> bf16(W_ih[gate][100+kk]); kk==18 -> bf16(bias); kk==19 ->
//     bf16(bias residual); kk>=20 -> 0. A supplies 1.0 at k=18 AND k=19.
//   H planes (ks 1..4, single bf16 plane each): base 688128 + (ks-1)*10752.
//     Slots 0..13 -> tiles 0..13 (r,z); slots 14..20 -> tiles 21..27 (hn).
//     REGION 3 (hn) uses gate rows 200+u (same n-gate rows as region 2)!
//   Global H region padded to 43520 ush (= 5440 f4) for tail staging reads.
//  STAGING BYTE MATH: X slab = 10752 ush * 2 B = 1344 f4; H = 5440 f4;
//   total 6784 f4 = 13 rounds * 512 + 2 wave-chunks (wid<2).
//  h (bf16 ushort, global): [rows][128]; cols 100..127 are 0.
//  Dynamic LDS: B0 [0,10752) | BH [10752,54272) | hmid [54272, +CHUNKS*64*136)
//   hmid row stride 136 ush (= 272 B, 16B-aligned — ds_read_b128 requirement).
// ---------------------------------------------------------------------------
__global__ __launch_bounds__(64) void precompute_kernel(
    const float* __restrict__ obs, const float* __restrict__ W_ih,
    const float* __restrict__ W_hh, const float* __restrict__ b_ih,
    const float* __restrict__ b_hh, const float* __restrict__ W1,
    const float* __restrict__ W2,
    unsigned short* __restrict__ Bg,
    float* __restrict__ W1T, float* __restrict__ W2T)
{
    int t = blockIdx.x * 64 + threadIdx.x;
    if (t < 688128) { // X slabs, one per o: 64 * 10752 positions (single plane)
        int o = t / 10752, r = t % 10752;
        int s = r / 512, r2 = r % 512;
        int j = r2 / 32, kk = r2 % 32;
        int region = s / 7;                 // 0=r,1=z,2=i_n
        int u = (s % 7) * 16 + j;
        unsigned short outv = 0;
        if (u < 100) {
            int gate = region * 100 + u;
            if (kk < 18) {
                outv = f2bf(W_ih[(size_t)gate * 118 + 100 + kk]);
            } else if (kk == 18 || kk == 19) { // bias hi / lo rows
                float bias = b_ih[gate] + (region < 2 ? b_hh[gate] : 0.f);
                const float* orow = obs + o * 100;
                const float* wrow = W_ih + (size_t)gate * 118;
                for (int k = 0; k < 100; ++k) bias = fmaf(orow[k], wrow[k], bias);
                if (kk == 18) outv = f2bf(bias);
                else          outv = f2bf(bias - bf2f(f2bf(bias)));
            }
        }
        int qr = kk >> 3, e = kk & 7;
        Bg[(size_t)o * 10752 + (size_t)((s * 4 + qr) * 16 + j) * 8 + e] = outv;
        return;
    }
    t -= 688128;
    if (t < 43008) { // H planes (ks 1..4): 4 * 10752 positions, single bf16 plane
        int ks = 1 + t / 10752, r = t % 10752;
        int s = r / 512, r2 = r % 512;
        int j = r2 / 32, kk = r2 % 32;
        int tt = (s < 14) ? s : s + 7;
        int region = tt / 7;
        int u = (tt % 7) * 16 + j;
        float wv = 0.f;
        if (u < 100) {
            // region 3 (h_n) uses the SAME n-gate rows (200+u) as region 2
            int gate = (region == 3 ? 2 : region) * 100 + u;
            int kh = (ks - 1) * 32 + kk;
            if (kh < 100) wv = W_hh[(size_t)gate * 100 + kh];
        }
        int qr = kk >> 3, e = kk & 7;
        Bg[(size_t)688128 + (size_t)(ks - 1) * 10752
           + (size_t)((s * 4 + qr) * 16 + j) * 8 + e] = f2bf(wv);
        return;
    }
    t -= 43008;
    if (t < 512) { // zero the H pad tail [731136, 731648)
        Bg[731136 + t] = 0;
        return;
    }
    t -= 512;
    if (t < 5000) { int g = t / 50, j = t % 50; W1T[t] = W1[j * 100 + g]; return; }
    t -= 5000;
    if (t < 1250) { int j = t / 25, i = t % 25; W2T[t] = W2[i * 50 + j]; }
}

// ---------------------------------------------------------------------------
// FUSED level pair (LW1, LW1-1), CHUNKS phase-1 chunks per block.
// Block = 512 thr (8 waves). Slabs staged ONCE. Phase 1 runs CHUNKS times
// (8 waves x 128 cells each, hmid rows disjoint). Phase 2 covers CHUNKS*64
// cells with CHUNKS*4 waves (CHUNKS=2 -> ALL 8 waves active, no idle).
// Still exactly 2 block barriers.
// ks0: 2 MFMAs/slot (axhi,axlo vs single bhi). H: 1 MFMA/slot.
// o-uniformity: blockBase is 128*CHUNKS-aligned and 128*CHUNKS <= cells/o
// for LW1 in {5,3} at CHUNKS=2 and LW1=1 at CHUNKS=1.
// ---------------------------------------------------------------------------
template<int LW1, bool LEAF1, bool LAST, int CHUNKS>
__global__ __launch_bounds__(512) void fused_pair(
    const unsigned short* __restrict__ Bg,
    const float* __restrict__ bhh,          // b_hh (for h_n bias rows 200+u)
    const float* __restrict__ samp,         // (O,P,63,8)
    const float* __restrict__ addr,         // (O,P,63,10)
    const unsigned short* __restrict__ hin, // [cellsIn][128] bf16 (unused if LEAF1)
    unsigned short* __restrict__ hout)      // [rowsOut][128] bf16
{
    extern __shared__ unsigned short smem[];
    unsigned short* B0   = smem;            // 10752 ush (single X plane)
    unsigned short* BH   = smem + 10752;    // 43520 ush (4 H planes + pad)
    unsigned short* hmid = smem + 54272;    // CHUNKS*64 rows x 136 ush

    const int tid = threadIdx.x;
    const int lane = tid & 63;
    const int wid = tid >> 6;
    const int j15 = lane & 15;
    const int qr = lane >> 4;
    // XCD swizzle (grid % 8 == 0)
    const int wk = (blockIdx.x & 7) * (gridDim.x >> 3) + (blockIdx.x >> 3);
    const int blockBase = wk * (128 * CHUNKS);   // first phase-1 cell
    const int o = blockBase >> (LW1 + 6);        // uniform per block

    // ---- stage X slab (1344 f4) + H planes (5440 f4) ONCE: 6784 f4 ----
    {
        const char* g0 = (const char*)(Bg + (size_t)o * 10752);
        const char* gH = (const char*)(Bg + 688128);
        char* l0 = (char*)smem;
        #pragma unroll
        for (int it = 0; it < 13; ++it) {
            const int base = it * 512 + wid * 64;      // f4 index, wave-uniform
            const int fi = base + lane;                // per-lane f4 index
            const char* src = (fi < 1344) ? g0 + (size_t)fi * 16
                                          : gH + (size_t)(fi - 1344) * 16;
            gload_lds16(src, l0 + (size_t)base * 16);
        }
        if (wid < 2) {                                 // tail: 6784-6656=128 f4
            const int base = 6656 + wid * 64;
            const int fi = base + lane;                // all >= 1344 -> H source
            gload_lds16(gH + (size_t)(fi - 1344) * 16, l0 + (size_t)base * 16);
        }
    }
    __syncthreads();   // barrier #1: slabs staged

    f32x4 acc[28];

    // ================= PHASE 1: CHUNKS chunks of 128 cells =================
    #pragma unroll 1
    for (int ch = 0; ch < CHUNKS; ++ch) {
        const int c0 = blockBase + ch * 128;
        const int c0w = c0 + wid * 16;

        #pragma unroll
        for (int t = 0; t < 28; ++t) acc[t] = (f32x4){0.f, 0.f, 0.f, 0.f};

        bf16x8 axhi, axlo;
        {
            const int w = 1 << LW1;
            const int cm = c0w + j15;
            const int opm = cm >> LW1;
            const int nodem = w - 1 + (cm & (w - 1));
            const size_t nb = (size_t)opm * 63 + nodem;
            float xv0=0.f,xv1=0.f,xv2=0.f,xv3=0.f,xv4=0.f,xv5=0.f,xv6=0.f,xv7=0.f;
            if (qr == 0) {
                const float4* s4 = (const float4*)(samp + nb * 8);
                float4 a = s4[0], b = s4[1];
                xv0=a.x; xv1=a.y; xv2=a.z; xv3=a.w; xv4=b.x; xv5=b.y; xv6=b.z; xv7=b.w;
            } else if (qr == 1) {
                const float2* a2 = (const float2*)(addr + nb * 10);
                float2 e0=a2[0], e1=a2[1], e2=a2[2], e3=a2[3];
                xv0=e0.x; xv1=e0.y; xv2=e1.x; xv3=e1.y; xv4=e2.x; xv5=e2.y; xv6=e3.x; xv7=e3.y;
            } else if (qr == 2) {
                xv0 = addr[nb * 10 + 8]; xv1 = addr[nb * 10 + 9];
                xv2 = 1.0f;                          // bias hi row k=18
                xv3 = 1.0f;                          // bias lo row k=19
            }
            #define CVT(e, val) { unsigned short hh = f2bf(val); \
                axhi[e] = (short)hh; axlo[e] = (short)f2bf((val) - bf2f(hh)); }
            CVT(0, xv0) CVT(1, xv1) CVT(2, xv2) CVT(3, xv3)
            CVT(4, xv4) CVT(5, xv5) CVT(6, xv6) CVT(7, xv7)
            #undef CVT
        }
        bf16x8 ah1[4];
        if constexpr (!LEAF1) {
            const size_t arow = (size_t)(c0w + j15) * 128 + qr * 8;
            #pragma unroll
            for (int m = 0; m < 4; ++m)
                ah1[m] = *(const bf16x8*)(hin + arow + m * 32);
        }

        #pragma unroll
        for (int s = 0; s < 21; ++s) {
            bf16x8 bhi = *(const bf16x8*)(B0 + ((s * 4 + qr) * 16 + j15) * 8);
            acc[s] = __builtin_amdgcn_mfma_f32_16x16x32_bf16(axhi, bhi, acc[s], 0, 0, 0);
            acc[s] = __builtin_amdgcn_mfma_f32_16x16x32_bf16(axlo, bhi, acc[s], 0, 0, 0);
        }
        if constexpr (!LEAF1) {
            #pragma unroll
            for (int ks = 1; ks <= 4; ++ks) {
                const unsigned short* hp = BH + (ks - 1) * 10752;
                #pragma unroll
                for (int s = 0; s < 21; ++s) {
                    const int d = (s < 14) ? s : s + 7;
                    bf16x8 bhi = *(const bf16x8*)(hp + ((s * 4 + qr) * 16 + j15) * 8);
                    acc[d] = __builtin_amdgcn_mfma_f32_16x16x32_bf16(ah1[ks - 1], bhi, acc[d], 0, 0, 0);
                }
            }
        }

        // ---- epilogue: gates + pairsum -> bf16 mid rows in LDS ----
        #pragma unroll
        for (int t = 0; t < 7; ++t) {
            const int u = t * 16 + j15;
            const float bh = (u < 100) ? bhh[200 + u] : 0.f;
            float hv0, hv1, hv2, hv3;
            #define GATE(reg, hvout) { \
                float rr = sigmoidf_(acc[t][reg]); \
                float zz = sigmoidf_(acc[t + 7][reg]); \
                float nn = tanhf_(acc[t + 14][reg] + rr * (acc[t + 21][reg] + bh)); \
                float hcv = 0.f; \
                if constexpr (!LEAF1) \
                    hcv = bf2f(hin[(size_t)(c0w + qr * 4 + reg) * 128 + u]); \
                hvout = nn + zz * (hcv - nn); }
            GATE(0, hv0) GATE(1, hv1) GATE(2, hv2) GATE(3, hv3)
            #undef GATE
            const int r0 = ch * 64 + wid * 8 + qr * 2;   // local mid row
            hmid[(r0)     * 136 + u] = f2bf(hv0 + hv1);
            hmid[(r0 + 1) * 136 + u] = f2bf(hv2 + hv3);
        }
    }
    // zero mid cols 112..127 for all CHUNKS*64 rows
    for (int f = tid; f < CHUNKS * 1024; f += 512)
        hmid[(f >> 4) * 136 + 112 + (f & 15)] = 0;
    __syncthreads();   // barrier #2: hmid complete

    // ====== PHASE 2: level LW1-1, CHUNKS*64 cells, CHUNKS*4 waves ======
    {
        constexpr int LW2 = LW1 - 1;
        if (wid >= CHUNKS * 4) return;      // no more barriers below
        const int c20 = blockBase >> 1;
        const int c2w = c20 + wid * 16;

        #pragma unroll
        for (int t = 0; t < 28; ++t) acc[t] = (f32x4){0.f, 0.f, 0.f, 0.f};

        bf16x8 axhi2, axlo2;
        {
            const int w = 1 << LW2;
            const int cm = c2w + j15;
            const int opm = cm >> LW2;
            const int nodem = w - 1 + (cm & (w - 1));
            const size_t nb = (size_t)opm * 63 + nodem;
            float xv0=0.f,xv1=0.f,xv2=0.f,xv3=0.f,xv4=0.f,xv5=0.f,xv6=0.f,xv7=0.f;
            if (qr == 0) {
                const float4* s4 = (const float4*)(samp + nb * 8);
                float4 a = s4[0], b = s4[1];
                xv0=a.x; xv1=a.y; xv2=a.z; xv3=a.w; xv4=b.x; xv5=b.y; xv6=b.z; xv7=b.w;
            } else if (qr == 1) {
                const float2* a2 = (const float2*)(addr + nb * 10);
                float2 e0=a2[0], e1=a2[1], e2=a2[2], e3=a2[3];
                xv0=e0.x; xv1=e0.y; xv2=e1.x; xv3=e1.y; xv4=e2.x; xv5=e2.y; xv6=e3.x; xv7=e3.y;
            } else if (qr == 2) {
                xv0 = addr[nb * 10 + 8]; xv1 = addr[nb * 10 + 9];
                xv2 = 1.0f;
                xv3 = 1.0f;
            }
            #define CVT(e, val) { unsigned short hh = f2bf(val); \
                axhi2[e] = (short)hh; axlo2[e] = (short)f2bf((val) - bf2f(hh)); }
            CVT(0, xv0) CVT(1, xv1) CVT(2, xv2) CVT(3, xv3)
            CVT(4, xv4) CVT(5, xv5) CVT(6, xv6) CVT(7, xv7)
            #undef CVT
        }

        #pragma unroll
        for (int s = 0; s < 21; ++s) {
            bf16x8 bhi = *(const bf16x8*)(B0 + ((s * 4 + qr) * 16 + j15) * 8);
            acc[s] = __builtin_amdgcn_mfma_f32_16x16x32_bf16(axhi2, bhi, acc[s], 0, 0, 0);
            acc[s] = __builtin_amdgcn_mfma_f32_16x16x32_bf16(axlo2, bhi, acc[s], 0, 0, 0);
        }
        #pragma unroll
        for (int ks = 1; ks <= 4; ++ks) {
            bf16x8 ahi = *(const bf16x8*)(hmid + (wid * 16 + j15) * 136
                                               + (ks - 1) * 32 + qr * 8);
            const unsigned short* hp = BH + (ks - 1) * 10752;
            #pragma unroll
            for (int s = 0; s < 21; ++s) {
                const int d = (s < 14) ? s : s + 7;
                bf16x8 bhi = *(const bf16x8*)(hp + ((s * 4 + qr) * 16 + j15) * 8);
                acc[d] = __builtin_amdgcn_mfma_f32_16x16x32_bf16(ahi, bhi, acc[d], 0, 0, 0);
            }
        }

        #pragma unroll
        for (int t = 0; t < 7; ++t) {
            const int u = t * 16 + j15;
            const float bh = (u < 100) ? bhh[200 + u] : 0.f;
            float hv0, hv1, hv2, hv3;
            #define GATE(reg, hvout) { \
                float rr = sigmoidf_(acc[t][reg]); \
                float zz = sigmoidf_(acc[t + 7][reg]); \
                float nn = tanhf_(acc[t + 14][reg] + rr * (acc[t + 21][reg] + bh)); \
                float hcv = bf2f(hmid[(wid * 16 + qr * 4 + reg) * 136 + u]); \
                hvout = nn + zz * (hcv - nn); }
            GATE(0, hv0) GATE(1, hv1) GATE(2, hv2) GATE(3, hv3)
            #undef GATE
            if (LAST) {
                unsigned short* r0 = hout + (size_t)(c2w + qr * 4) * 128 + u;
                r0[0]   = f2bf(hv0);
                r0[128] = f2bf(hv1);
                r0[256] = f2bf(hv2);
                r0[384] = f2bf(hv3);
            } else {
                unsigned short* r0 = hout + (size_t)((c2w >> 1) + qr * 2) * 128 + u;
                r0[0]   = f2bf(hv0 + hv1);
                r0[128] = f2bf(hv2 + hv3);
            }
        }
        const int u2 = 112 + j15;
        if (LAST) {
            #pragma unroll
            for (int reg = 0; reg < 4; ++reg)
                hout[(size_t)(c2w + qr * 4 + reg) * 128 + u2] = 0;
        } else {
            #pragma unroll
            for (int p = 0; p < 2; ++p)
                hout[(size_t)((c2w >> 1) + qr * 2 + p) * 128 + u2] = 0;
        }
    }
}

// ---------------------------------------------------------------------------
// MLP head + logsumexp (bf16 h input — verified).
// ---------------------------------------------------------------------------
__global__ __launch_bounds__(256) void mlp_lse(
    const unsigned short* __restrict__ h0,  // [4096][128] bf16
    const float* __restrict__ W1T,  // [100][50]
    const float* __restrict__ b1,
    const float* __restrict__ W2T,  // [50][25]
    const float* __restrict__ b2,
    const float* __restrict__ W3,
    const float* __restrict__ b3,
    float* __restrict__ out)
{
    __shared__ float hs[64 * 101];
    __shared__ float w1s[5008];
    __shared__ float w2s[1250];
    __shared__ float y1s[64 * 50];

    const int o = blockIdx.x;
    const int tid = threadIdx.x;
    const int lane = tid & 63;
    const int wid = tid >> 6;

    for (int f = tid; f < 6400; f += 256) {
        int cl = f / 100, g = f - cl * 100;
        hs[cl * 101 + g] = bf2f(h0[(size_t)(o * 64 + cl) * 128 + g]);
    }
    for (int f = tid; f < 5000; f += 256) w1s[f] = W1T[f];
    for (int f = tid; f < 1250; f += 256) w2s[f] = W2T[f];
    __syncthreads();

    const int jbase = wid * 13;
    const int jn = (wid < 3) ? 13 : 11;       // 13+13+13+11 = 50
    float y1[13];
    #pragma unroll
    for (int jj = 0; jj < 13; ++jj) y1[jj] = b1[jbase + jj < 50 ? jbase + jj : 49];
    #pragma unroll 2
    for (int g = 0; g < 100; ++g) {
        float rg = hs[lane * 101 + g];
        const float* wr = w1s + g * 50 + jbase;
        #pragma unroll
        for (int jj = 0; jj < 13; ++jj) y1[jj] = fmaf(rg, wr[jj], y1[jj]);
    }
    #pragma unroll
    for (int jj = 0; jj < 13; ++jj)
        if (jj < jn) y1s[lane * 50 + jbase + jj] = y1[jj];
    __syncthreads();
    if (wid != 0) return;

    const int p = lane;
    float y2[25];
    #pragma unroll
    for (int i = 0; i < 25; ++i) y2[i] = b2[i];
    #pragma unroll 2
    for (int j = 0; j < 50; ++j) {
        float v = fmaxf(y1s[p * 50 + j], 0.0f);
        const float* wr = w2s + j * 25;
        #pragma unroll
        for (int i = 0; i < 25; ++i) y2[i] = fmaf(v, wr[i], y2[i]);
    }

    float cv = b3[0];
    #pragma unroll
    for (int i = 0; i < 25; ++i) cv = fmaf(fmaxf(y2[i], 0.0f), W3[i], cv);

    float m = cv;
    #pragma unroll
    for (int s = 1; s < 64; s <<= 1) m = fmaxf(m, __shfl_xor(m, s));
    float e = __expf(cv - m);
    #pragma unroll
    for (int s = 1; s < 64; s <<= 1) e += __shfl_xor(e, s);
    if (p == 0) out[o] = m + __logf(e) - 4.1588830833596715f; // log(64)
}

// ---------------------------------------------------------------------------
extern "C" void kernel_launch(void* const* d_in, const int* in_sizes, int n_in,
                              void* d_out, int out_size, void* d_ws, size_t ws_size,
                              hipStream_t stream)
{
    const float* obs  = (const float*)d_in[0];
    const float* samp = (const float*)d_in[1];
    const float* addr = (const float*)d_in[2];
    const float* W_ih = (const float*)d_in[3];
    const float* W_hh = (const float*)d_in[4];
    const float* b_ih = (const float*)d_in[5];
    const float* b_hh = (const float*)d_in[6];
    const float* W1   = (const float*)d_in[7];
    const float* b1   = (const float*)d_in[8];
    const float* W2   = (const float*)d_in[9];
    const float* b2   = (const float*)d_in[10];
    const float* W3   = (const float*)d_in[11];
    const float* b3   = (const float*)d_in[12];
    float* out = (float*)d_out;

    float* ws = (float*)d_ws;
    // Bg: 64*10752 (X) + 43520 (H incl 512-ush pad) = 731648 ush = 365824 floats
    unsigned short* Bg = (unsigned short*)ws;
    float* W1T = ws + 365824;                       // 5000
    float* W2T = ws + 370824;                       // 1250
    unsigned short* hU1 = (unsigned short*)(ws + 372080);   // 32768*128 ush
    unsigned short* hU2 = (unsigned short*)(ws + 2469232);  // 8192*128 ush
    unsigned short* hU3 = (unsigned short*)(ws + 2993520);  // 4096*128 ush

    const int LDS2 = (10752 + 43520 + 2 * 8704) * 2;  // 143360 B (CHUNKS=2)
    const int LDS1 = (10752 + 43520 + 1 * 8704) * 2;  // 125952 B (CHUNKS=1)
    (void)hipFuncSetAttribute((const void*)fused_pair<5, true, false, 2>,
        hipFuncAttributeMaxDynamicSharedMemorySize, LDS2);
    (void)hipFuncSetAttribute((const void*)fused_pair<3, false, false, 2>,
        hipFuncAttributeMaxDynamicSharedMemorySize, LDS2);
    (void)hipFuncSetAttribute((const void*)fused_pair<1, false, true, 1>,
        hipFuncAttributeMaxDynamicSharedMemorySize, LDS1);

    // threads: 688128 (X) + 43008 (H) + 512 (H pad zero) + 5000 + 1250 = 737898
    precompute_kernel<<<(737898 + 63) / 64, 64, 0, stream>>>(
        obs, W_ih, W_hh, b_ih, b_hh, W1, W2, Bg, W1T, W2T);

    // pair A: leaf(lw=5) + L4 — 131072 cells -> 32768 rows (hU1), 2 chunks/block
    fused_pair<5, true, false, 2><<<512, 512, LDS2, stream>>>(
        Bg, b_hh, samp, addr, nullptr, hU1);
    // pair B: L3 + L2 — 32768 cells (hU1) -> 8192 rows (hU2), 2 chunks/block
    fused_pair<3, false, false, 2><<<128, 512, LDS2, stream>>>(
        Bg, b_hh, samp, addr, hU1, hU2);
    // pair C: L1 + L0 — 8192 cells (hU2) -> 4096 rows (hU3), single chunk
    // (LW1=1 has only 128 cells per o — 256-cell blocks would straddle two o)
    fused_pair<1, false, true, 1><<<64, 512, LDS1, stream>>>(
        Bg, b_hh, samp, addr, hU2, hU3);

    mlp_lse<<<64, 256, 0, stream>>>(hU3, W1T, b1, W2T, b2, W3, b3, out);
}

// Round 23
// 127.009 us; speedup vs baseline: 1.0925x; 1.0925x over previous
//
#include <hip/hip_runtime.h>
#include <hip/hip_bf16.h>

typedef __attribute__((ext_vector_type(8))) short bf16x8;
typedef __attribute__((ext_vector_type(4))) float f32x4;

__device__ __forceinline__ float sigmoidf_(float x){ return 1.0f/(1.0f+__expf(-x)); }
__device__ __forceinline__ float tanhf_(float x){ return 1.0f - 2.0f/(1.0f+__expf(2.0f*x)); }
__device__ __forceinline__ unsigned short f2bf(float f){
    __hip_bfloat16 b = __float2bfloat16(f);
    return *reinterpret_cast<unsigned short*>(&b);
}
__device__ __forceinline__ float bf2f(unsigned short u){
    __hip_bfloat16 b = *reinterpret_cast<__hip_bfloat16*>(&u);
    return __bfloat162float(b);
}
// async global->LDS, 16B per lane; LDS dest = wave-uniform base (+lane*16 implicit)
__device__ __forceinline__ void gload_lds16(const void* gsrc, void* ldst){
    __builtin_amdgcn_global_load_lds(
        (const __attribute__((address_space(1))) unsigned int*)gsrc,
        (__attribute__((address_space(3))) unsigned int*)ldst,
        16, 0, 0);
}

// ---------------------------------------------------------------------------
// Layouts (identical to R21 — verified):
//  Bg (ushort):
//   X slabs 0..63 (per-o, SINGLE bf16 plane): 10752 ush = [21 slots][4 qr][16 j][8 e].
//     kk<18 -> bf16(W_ih[gate][100+kk]); kk==18 -> bf16(bias); kk==19 ->
//     bf16(bias residual); kk>=20 -> 0. A supplies 1.0 at k=18 AND k=19.
//   H planes (ks 1..4, single bf16 plane each): base 688128 + (ks-1)*10752.
//     Slots 0..13 -> tiles 0..13 (r,z); slots 14..20 -> tiles 21..27 (hn).
//     REGION 3 (hn) uses gate rows 200+u (same n-gate rows as region 2)!
//   Global H region padded to 43520 ush (= 5440 f4) for tail staging reads.
//  STAGING BYTE MATH: X slab = 10752 ush * 2 B = 1344 f4; H = 5440 f4;
//   total 6784 f4 = 13 rounds * 512 + 2 wave-chunks (wid<2).
//  h (bf16 ushort, global): [rows][128]; cols 100..127 are 0.
//  Dynamic LDS: B0 [0,10752) | BH [10752,54272) | hmid [54272, +CHUNKS*64*136)
//   hmid row stride 136 ush (= 272 B, 16B-aligned — ds_read_b128 requirement).
//  LAUNCH RULE (R22 lesson): CHUNKS=2 only when grid stays >= 256 blocks;
//   below that, consolidating work into fewer blocks idles CUs.
// ---------------------------------------------------------------------------
__global__ __launch_bounds__(64) void precompute_kernel(
    const float* __restrict__ obs, const float* __restrict__ W_ih,
    const float* __restrict__ W_hh, const float* __restrict__ b_ih,
    const float* __restrict__ b_hh, const float* __restrict__ W1,
    const float* __restrict__ W2,
    unsigned short* __restrict__ Bg,
    float* __restrict__ W1T, float* __restrict__ W2T)
{
    int t = blockIdx.x * 64 + threadIdx.x;
    if (t < 688128) { // X slabs, one per o: 64 * 10752 positions (single plane)
        int o = t / 10752, r = t % 10752;
        int s = r / 512, r2 = r % 512;
        int j = r2 / 32, kk = r2 % 32;
        int region = s / 7;                 // 0=r,1=z,2=i_n
        int u = (s % 7) * 16 + j;
        unsigned short outv = 0;
        if (u < 100) {
            int gate = region * 100 + u;
            if (kk < 18) {
                outv = f2bf(W_ih[(size_t)gate * 118 + 100 + kk]);
            } else if (kk == 18 || kk == 19) { // bias hi / lo rows
                float bias = b_ih[gate] + (region < 2 ? b_hh[gate] : 0.f);
                const float* orow = obs + o * 100;
                const float* wrow = W_ih + (size_t)gate * 118;
                for (int k = 0; k < 100; ++k) bias = fmaf(orow[k], wrow[k], bias);
                if (kk == 18) outv = f2bf(bias);
                else          outv = f2bf(bias - bf2f(f2bf(bias)));
            }
        }
        int qr = kk >> 3, e = kk & 7;
        Bg[(size_t)o * 10752 + (size_t)((s * 4 + qr) * 16 + j) * 8 + e] = outv;
        return;
    }
    t -= 688128;
    if (t < 43008) { // H planes (ks 1..4): 4 * 10752 positions, single bf16 plane
        int ks = 1 + t / 10752, r = t % 10752;
        int s = r / 512, r2 = r % 512;
        int j = r2 / 32, kk = r2 % 32;
        int tt = (s < 14) ? s : s + 7;
        int region = tt / 7;
        int u = (tt % 7) * 16 + j;
        float wv = 0.f;
        if (u < 100) {
            // region 3 (h_n) uses the SAME n-gate rows (200+u) as region 2
            int gate = (region == 3 ? 2 : region) * 100 + u;
            int kh = (ks - 1) * 32 + kk;
            if (kh < 100) wv = W_hh[(size_t)gate * 100 + kh];
        }
        int qr = kk >> 3, e = kk & 7;
        Bg[(size_t)688128 + (size_t)(ks - 1) * 10752
           + (size_t)((s * 4 + qr) * 16 + j) * 8 + e] = f2bf(wv);
        return;
    }
    t -= 43008;
    if (t < 512) { // zero the H pad tail [731136, 731648)
        Bg[731136 + t] = 0;
        return;
    }
    t -= 512;
    if (t < 5000) { int g = t / 50, j = t % 50; W1T[t] = W1[j * 100 + g]; return; }
    t -= 5000;
    if (t < 1250) { int j = t / 25, i = t % 25; W2T[t] = W2[i * 50 + j]; }
}

// ---------------------------------------------------------------------------
// FUSED level pair (LW1, LW1-1), CHUNKS phase-1 chunks per block.
// Block = 512 thr (8 waves). Slabs staged ONCE. Phase 1 runs CHUNKS times
// (8 waves x 128 cells each, hmid rows disjoint). Phase 2 covers CHUNKS*64
// cells with CHUNKS*4 waves (CHUNKS=2 -> ALL 8 waves active, no idle).
// Still exactly 2 block barriers.
// ks0: 2 MFMAs/slot (axhi,axlo vs single bhi). H: 1 MFMA/slot.
// ---------------------------------------------------------------------------
template<int LW1, bool LEAF1, bool LAST, int CHUNKS>
__global__ __launch_bounds__(512) void fused_pair(
    const unsigned short* __restrict__ Bg,
    const float* __restrict__ bhh,          // b_hh (for h_n bias rows 200+u)
    const float* __restrict__ samp,         // (O,P,63,8)
    const float* __restrict__ addr,         // (O,P,63,10)
    const unsigned short* __restrict__ hin, // [cellsIn][128] bf16 (unused if LEAF1)
    unsigned short* __restrict__ hout)      // [rowsOut][128] bf16
{
    extern __shared__ unsigned short smem[];
    unsigned short* B0   = smem;            // 10752 ush (single X plane)
    unsigned short* BH   = smem + 10752;    // 43520 ush (4 H planes + pad)
    unsigned short* hmid = smem + 54272;    // CHUNKS*64 rows x 136 ush

    const int tid = threadIdx.x;
    const int lane = tid & 63;
    const int wid = tid >> 6;
    const int j15 = lane & 15;
    const int qr = lane >> 4;
    // XCD swizzle (grid % 8 == 0)
    const int wk = (blockIdx.x & 7) * (gridDim.x >> 3) + (blockIdx.x >> 3);
    const int blockBase = wk * (128 * CHUNKS);   // first phase-1 cell
    const int o = blockBase >> (LW1 + 6);        // uniform per block

    // ---- stage X slab (1344 f4) + H planes (5440 f4) ONCE: 6784 f4 ----
    {
        const char* g0 = (const char*)(Bg + (size_t)o * 10752);
        const char* gH = (const char*)(Bg + 688128);
        char* l0 = (char*)smem;
        #pragma unroll
        for (int it = 0; it < 13; ++it) {
            const int base = it * 512 + wid * 64;      // f4 index, wave-uniform
            const int fi = base + lane;                // per-lane f4 index
            const char* src = (fi < 1344) ? g0 + (size_t)fi * 16
                                          : gH + (size_t)(fi - 1344) * 16;
            gload_lds16(src, l0 + (size_t)base * 16);
        }
        if (wid < 2) {                                 // tail: 6784-6656=128 f4
            const int base = 6656 + wid * 64;
            const int fi = base + lane;                // all >= 1344 -> H source
            gload_lds16(gH + (size_t)(fi - 1344) * 16, l0 + (size_t)base * 16);
        }
    }
    __syncthreads();   // barrier #1: slabs staged

    f32x4 acc[28];

    // ================= PHASE 1: CHUNKS chunks of 128 cells =================
    #pragma unroll 1
    for (int ch = 0; ch < CHUNKS; ++ch) {
        const int c0 = blockBase + ch * 128;
        const int c0w = c0 + wid * 16;

        #pragma unroll
        for (int t = 0; t < 28; ++t) acc[t] = (f32x4){0.f, 0.f, 0.f, 0.f};

        bf16x8 axhi, axlo;
        {
            const int w = 1 << LW1;
            const int cm = c0w + j15;
            const int opm = cm >> LW1;
            const int nodem = w - 1 + (cm & (w - 1));
            const size_t nb = (size_t)opm * 63 + nodem;
            float xv0=0.f,xv1=0.f,xv2=0.f,xv3=0.f,xv4=0.f,xv5=0.f,xv6=0.f,xv7=0.f;
            if (qr == 0) {
                const float4* s4 = (const float4*)(samp + nb * 8);
                float4 a = s4[0], b = s4[1];
                xv0=a.x; xv1=a.y; xv2=a.z; xv3=a.w; xv4=b.x; xv5=b.y; xv6=b.z; xv7=b.w;
            } else if (qr == 1) {
                const float2* a2 = (const float2*)(addr + nb * 10);
                float2 e0=a2[0], e1=a2[1], e2=a2[2], e3=a2[3];
                xv0=e0.x; xv1=e0.y; xv2=e1.x; xv3=e1.y; xv4=e2.x; xv5=e2.y; xv6=e3.x; xv7=e3.y;
            } else if (qr == 2) {
                xv0 = addr[nb * 10 + 8]; xv1 = addr[nb * 10 + 9];
                xv2 = 1.0f;                          // bias hi row k=18
                xv3 = 1.0f;                          // bias lo row k=19
            }
            #define CVT(e, val) { unsigned short hh = f2bf(val); \
                axhi[e] = (short)hh; axlo[e] = (short)f2bf((val) - bf2f(hh)); }
            CVT(0, xv0) CVT(1, xv1) CVT(2, xv2) CVT(3, xv3)
            CVT(4, xv4) CVT(5, xv5) CVT(6, xv6) CVT(7, xv7)
            #undef CVT
        }
        bf16x8 ah1[4];
        if constexpr (!LEAF1) {
            const size_t arow = (size_t)(c0w + j15) * 128 + qr * 8;
            #pragma unroll
            for (int m = 0; m < 4; ++m)
                ah1[m] = *(const bf16x8*)(hin + arow + m * 32);
        }

        #pragma unroll
        for (int s = 0; s < 21; ++s) {
            bf16x8 bhi = *(const bf16x8*)(B0 + ((s * 4 + qr) * 16 + j15) * 8);
            acc[s] = __builtin_amdgcn_mfma_f32_16x16x32_bf16(axhi, bhi, acc[s], 0, 0, 0);
            acc[s] = __builtin_amdgcn_mfma_f32_16x16x32_bf16(axlo, bhi, acc[s], 0, 0, 0);
        }
        if constexpr (!LEAF1) {
            #pragma unroll
            for (int ks = 1; ks <= 4; ++ks) {
                const unsigned short* hp = BH + (ks - 1) * 10752;
                #pragma unroll
                for (int s = 0; s < 21; ++s) {
                    const int d = (s < 14) ? s : s + 7;
                    bf16x8 bhi = *(const bf16x8*)(hp + ((s * 4 + qr) * 16 + j15) * 8);
                    acc[d] = __builtin_amdgcn_mfma_f32_16x16x32_bf16(ah1[ks - 1], bhi, acc[d], 0, 0, 0);
                }
            }
        }

        // ---- epilogue: gates + pairsum -> bf16 mid rows in LDS ----
        #pragma unroll
        for (int t = 0; t < 7; ++t) {
            const int u = t * 16 + j15;
            const float bh = (u < 100) ? bhh[200 + u] : 0.f;
            float hv0, hv1, hv2, hv3;
            #define GATE(reg, hvout) { \
                float rr = sigmoidf_(acc[t][reg]); \
                float zz = sigmoidf_(acc[t + 7][reg]); \
                float nn = tanhf_(acc[t + 14][reg] + rr * (acc[t + 21][reg] + bh)); \
                float hcv = 0.f; \
                if constexpr (!LEAF1) \
                    hcv = bf2f(hin[(size_t)(c0w + qr * 4 + reg) * 128 + u]); \
                hvout = nn + zz * (hcv - nn); }
            GATE(0, hv0) GATE(1, hv1) GATE(2, hv2) GATE(3, hv3)
            #undef GATE
            const int r0 = ch * 64 + wid * 8 + qr * 2;   // local mid row
            hmid[(r0)     * 136 + u] = f2bf(hv0 + hv1);
            hmid[(r0 + 1) * 136 + u] = f2bf(hv2 + hv3);
        }
    }
    // zero mid cols 112..127 for all CHUNKS*64 rows
    for (int f = tid; f < CHUNKS * 1024; f += 512)
        hmid[(f >> 4) * 136 + 112 + (f & 15)] = 0;
    __syncthreads();   // barrier #2: hmid complete

    // ====== PHASE 2: level LW1-1, CHUNKS*64 cells, CHUNKS*4 waves ======
    {
        constexpr int LW2 = LW1 - 1;
        if (wid >= CHUNKS * 4) return;      // no more barriers below
        const int c20 = blockBase >> 1;
        const int c2w = c20 + wid * 16;

        #pragma unroll
        for (int t = 0; t < 28; ++t) acc[t] = (f32x4){0.f, 0.f, 0.f, 0.f};

        bf16x8 axhi2, axlo2;
        {
            const int w = 1 << LW2;
            const int cm = c2w + j15;
            const int opm = cm >> LW2;
            const int nodem = w - 1 + (cm & (w - 1));
            const size_t nb = (size_t)opm * 63 + nodem;
            float xv0=0.f,xv1=0.f,xv2=0.f,xv3=0.f,xv4=0.f,xv5=0.f,xv6=0.f,xv7=0.f;
            if (qr == 0) {
                const float4* s4 = (const float4*)(samp + nb * 8);
                float4 a = s4[0], b = s4[1];
                xv0=a.x; xv1=a.y; xv2=a.z; xv3=a.w; xv4=b.x; xv5=b.y; xv6=b.z; xv7=b.w;
            } else if (qr == 1) {
                const float2* a2 = (const float2*)(addr + nb * 10);
                float2 e0=a2[0], e1=a2[1], e2=a2[2], e3=a2[3];
                xv0=e0.x; xv1=e0.y; xv2=e1.x; xv3=e1.y; xv4=e2.x; xv5=e2.y; xv6=e3.x; xv7=e3.y;
            } else if (qr == 2) {
                xv0 = addr[nb * 10 + 8]; xv1 = addr[nb * 10 + 9];
                xv2 = 1.0f;
                xv3 = 1.0f;
            }
            #define CVT(e, val) { unsigned short hh = f2bf(val); \
                axhi2[e] = (short)hh; axlo2[e] = (short)f2bf((val) - bf2f(hh)); }
            CVT(0, xv0) CVT(1, xv1) CVT(2, xv2) CVT(3, xv3)
            CVT(4, xv4) CVT(5, xv5) CVT(6, xv6) CVT(7, xv7)
            #undef CVT
        }

        #pragma unroll
        for (int s = 0; s < 21; ++s) {
            bf16x8 bhi = *(const bf16x8*)(B0 + ((s * 4 + qr) * 16 + j15) * 8);
            acc[s] = __builtin_amdgcn_mfma_f32_16x16x32_bf16(axhi2, bhi, acc[s], 0, 0, 0);
            acc[s] = __builtin_amdgcn_mfma_f32_16x16x32_bf16(axlo2, bhi, acc[s], 0, 0, 0);
        }
        #pragma unroll
        for (int ks = 1; ks <= 4; ++ks) {
            bf16x8 ahi = *(const bf16x8*)(hmid + (wid * 16 + j15) * 136
                                               + (ks - 1) * 32 + qr * 8);
            const unsigned short* hp = BH + (ks - 1) * 10752;
            #pragma unroll
            for (int s = 0; s < 21; ++s) {
                const int d = (s < 14) ? s : s + 7;
                bf16x8 bhi = *(const bf16x8*)(hp + ((s * 4 + qr) * 16 + j15) * 8);
                acc[d] = __builtin_amdgcn_mfma_f32_16x16x32_bf16(ahi, bhi, acc[d], 0, 0, 0);
            }
        }

        #pragma unroll
        for (int t = 0; t < 7; ++t) {
            const int u = t * 16 + j15;
            const float bh = (u < 100) ? bhh[200 + u] : 0.f;
            float hv0, hv1, hv2, hv3;
            #define GATE(reg, hvout) { \
                float rr = sigmoidf_(acc[t][reg]); \
                float zz = sigmoidf_(acc[t + 7][reg]); \
                float nn = tanhf_(acc[t + 14][reg] + rr * (acc[t + 21][reg] + bh)); \
                float hcv = bf2f(hmid[(wid * 16 + qr * 4 + reg) * 136 + u]); \
                hvout = nn + zz * (hcv - nn); }
            GATE(0, hv0) GATE(1, hv1) GATE(2, hv2) GATE(3, hv3)
            #undef GATE
            if (LAST) {
                unsigned short* r0 = hout + (size_t)(c2w + qr * 4) * 128 + u;
                r0[0]   = f2bf(hv0);
                r0[128] = f2bf(hv1);
                r0[256] = f2bf(hv2);
                r0[384] = f2bf(hv3);
            } else {
                unsigned short* r0 = hout + (size_t)((c2w >> 1) + qr * 2) * 128 + u;
                r0[0]   = f2bf(hv0 + hv1);
                r0[128] = f2bf(hv2 + hv3);
            }
        }
        const int u2 = 112 + j15;
        if (LAST) {
            #pragma unroll
            for (int reg = 0; reg < 4; ++reg)
                hout[(size_t)(c2w + qr * 4 + reg) * 128 + u2] = 0;
        } else {
            #pragma unroll
            for (int p = 0; p < 2; ++p)
                hout[(size_t)((c2w >> 1) + qr * 2 + p) * 128 + u2] = 0;
        }
    }
}

// ---------------------------------------------------------------------------
// MLP head + logsumexp (bf16 h input — verified).
// ---------------------------------------------------------------------------
__global__ __launch_bounds__(256) void mlp_lse(
    const unsigned short* __restrict__ h0,  // [4096][128] bf16
    const float* __restrict__ W1T,  // [100][50]
    const float* __restrict__ b1,
    const float* __restrict__ W2T,  // [50][25]
    const float* __restrict__ b2,
    const float* __restrict__ W3,
    const float* __restrict__ b3,
    float* __restrict__ out)
{
    __shared__ float hs[64 * 101];
    __shared__ float w1s[5008];
    __shared__ float w2s[1250];
    __shared__ float y1s[64 * 50];

    const int o = blockIdx.x;
    const int tid = threadIdx.x;
    const int lane = tid & 63;
    const int wid = tid >> 6;

    for (int f = tid; f < 6400; f += 256) {
        int cl = f / 100, g = f - cl * 100;
        hs[cl * 101 + g] = bf2f(h0[(size_t)(o * 64 + cl) * 128 + g]);
    }
    for (int f = tid; f < 5000; f += 256) w1s[f] = W1T[f];
    for (int f = tid; f < 1250; f += 256) w2s[f] = W2T[f];
    __syncthreads();

    const int jbase = wid * 13;
    const int jn = (wid < 3) ? 13 : 11;       // 13+13+13+11 = 50
    float y1[13];
    #pragma unroll
    for (int jj = 0; jj < 13; ++jj) y1[jj] = b1[jbase + jj < 50 ? jbase + jj : 49];
    #pragma unroll 2
    for (int g = 0; g < 100; ++g) {
        float rg = hs[lane * 101 + g];
        const float* wr = w1s + g * 50 + jbase;
        #pragma unroll
        for (int jj = 0; jj < 13; ++jj) y1[jj] = fmaf(rg, wr[jj], y1[jj]);
    }
    #pragma unroll
    for (int jj = 0; jj < 13; ++jj)
        if (jj < jn) y1s[lane * 50 + jbase + jj] = y1[jj];
    __syncthreads();
    if (wid != 0) return;

    const int p = lane;
    float y2[25];
    #pragma unroll
    for (int i = 0; i < 25; ++i) y2[i] = b2[i];
    #pragma unroll 2
    for (int j = 0; j < 50; ++j) {
        float v = fmaxf(y1s[p * 50 + j], 0.0f);
        const float* wr = w2s + j * 25;
        #pragma unroll
        for (int i = 0; i < 25; ++i) y2[i] = fmaf(v, wr[i], y2[i]);
    }

    float cv = b3[0];
    #pragma unroll
    for (int i = 0; i < 25; ++i) cv = fmaf(fmaxf(y2[i], 0.0f), W3[i], cv);

    float m = cv;
    #pragma unroll
    for (int s = 1; s < 64; s <<= 1) m = fmaxf(m, __shfl_xor(m, s));
    float e = __expf(cv - m);
    #pragma unroll
    for (int s = 1; s < 64; s <<= 1) e += __shfl_xor(e, s);
    if (p == 0) out[o] = m + __logf(e) - 4.1588830833596715f; // log(64)
}

// ---------------------------------------------------------------------------
extern "C" void kernel_launch(void* const* d_in, const int* in_sizes, int n_in,
                              void* d_out, int out_size, void* d_ws, size_t ws_size,
                              hipStream_t stream)
{
    const float* obs  = (const float*)d_in[0];
    const float* samp = (const float*)d_in[1];
    const float* addr = (const float*)d_in[2];
    const float* W_ih = (const float*)d_in[3];
    const float* W_hh = (const float*)d_in[4];
    const float* b_ih = (const float*)d_in[5];
    const float* b_hh = (const float*)d_in[6];
    const float* W1   = (const float*)d_in[7];
    const float* b1   = (const float*)d_in[8];
    const float* W2   = (const float*)d_in[9];
    const float* b2   = (const float*)d_in[10];
    const float* W3   = (const float*)d_in[11];
    const float* b3   = (const float*)d_in[12];
    float* out = (float*)d_out;

    float* ws = (float*)d_ws;
    // Bg: 64*10752 (X) + 43520 (H incl 512-ush pad) = 731648 ush = 365824 floats
    unsigned short* Bg = (unsigned short*)ws;
    float* W1T = ws + 365824;                       // 5000
    float* W2T = ws + 370824;                       // 1250
    unsigned short* hU1 = (unsigned short*)(ws + 372080);   // 32768*128 ush
    unsigned short* hU2 = (unsigned short*)(ws + 2469232);  // 8192*128 ush
    unsigned short* hU3 = (unsigned short*)(ws + 2993520);  // 4096*128 ush

    const int LDS2 = (10752 + 43520 + 2 * 8704) * 2;  // 143360 B (CHUNKS=2)
    const int LDS1 = (10752 + 43520 + 1 * 8704) * 2;  // 125952 B (CHUNKS=1)
    (void)hipFuncSetAttribute((const void*)fused_pair<5, true, false, 2>,
        hipFuncAttributeMaxDynamicSharedMemorySize, LDS2);
    (void)hipFuncSetAttribute((const void*)fused_pair<3, false, false, 1>,
        hipFuncAttributeMaxDynamicSharedMemorySize, LDS1);
    (void)hipFuncSetAttribute((const void*)fused_pair<1, false, true, 1>,
        hipFuncAttributeMaxDynamicSharedMemorySize, LDS1);

    // threads: 688128 (X) + 43008 (H) + 512 (H pad zero) + 5000 + 1250 = 737898
    precompute_kernel<<<(737898 + 63) / 64, 64, 0, stream>>>(
        obs, W_ih, W_hh, b_ih, b_hh, W1, W2, Bg, W1T, W2T);

    // pair A: leaf(lw=5) + L4 — 131072 cells -> 32768 rows (hU1), 2 chunks/block
    // (grid 512 >= 256 CUs: chunking pays — R22 measured pairA 67 -> 59 us)
    fused_pair<5, true, false, 2><<<512, 512, LDS2, stream>>>(
        Bg, b_hh, samp, addr, nullptr, hU1);
    // pair B: L3 + L2 — 32768 cells (hU1) -> 8192 rows (hU2), 1 chunk/block
    // (grid must stay 256 = #CUs; CHUNKS=2 at grid 128 idled half the machine, R22)
    fused_pair<3, false, false, 1><<<256, 512, LDS1, stream>>>(
        Bg, b_hh, samp, addr, hU1, hU2);
    // pair C: L1 + L0 — 8192 cells (hU2) -> 4096 rows (hU3), single chunk
    fused_pair<1, false, true, 1><<<64, 512, LDS1, stream>>>(
        Bg, b_hh, samp, addr, hU2, hU3);

    mlp_lse<<<64, 256, 0, stream>>>(hU3, W1T, b1, W2T, b2, W3, b3, out);
}